// Round 1
// baseline (1467.385 us; speedup 1.0000x reference)
//
#include <hip/hip_runtime.h>
#include <stdint.h>

// out[n,c,o] = sum_i x[n,c,i]*W[c,o,i] + b[c,o]
// x (N,C,IN) fp32, W (C,OUT,IN) fp32, b (C,OUT) fp32
#define N_TOT 32768
#define C_CH  8
#define K_IN  512
#define OUT_F 512
#define NKS   (K_IN / 32)                      // 16 k-steps of 32
#define WB_ELEMS ((size_t)C_CH * OUT_F * K_IN) // 2,097,152 bf16 elements

typedef __attribute__((ext_vector_type(4))) float f32x4;
typedef __attribute__((ext_vector_type(8))) short s16x8;

// 8 fp32 -> 8 bf16 (RNE) via v_cvt_pk_bf16_f32 (gfx950 has the instr, no builtin).
__device__ __forceinline__ s16x8 cvt_bf16x8(f32x4 lo, f32x4 hi) {
  uint32_t p0, p1, p2, p3;
  asm("v_cvt_pk_bf16_f32 %0, %1, %2" : "=v"(p0) : "v"(lo.x), "v"(lo.y));
  asm("v_cvt_pk_bf16_f32 %0, %1, %2" : "=v"(p1) : "v"(lo.z), "v"(lo.w));
  asm("v_cvt_pk_bf16_f32 %0, %1, %2" : "=v"(p2) : "v"(hi.x), "v"(hi.y));
  asm("v_cvt_pk_bf16_f32 %0, %1, %2" : "=v"(p3) : "v"(hi.z), "v"(hi.w));
  union { uint32_t u[4]; s16x8 v; } r;
  r.u[0] = p0; r.u[1] = p1; r.u[2] = p2; r.u[3] = p3;
  return r.v;
}

// One-time (per launch) W fp32 -> bf16, same [c][o][k] layout. 8 MiB read, 4 MiB write (~3 us).
extern "C" __global__ void __launch_bounds__(256, 4)
wconv(const float* __restrict__ w, unsigned short* __restrict__ wb) {
  const size_t i = ((size_t)blockIdx.x * 256 + threadIdx.x) * 8;
  f32x4 lo = *(const f32x4*)(w + i);
  f32x4 hi = *(const f32x4*)(w + i + 4);
  *(s16x8*)(wb + i) = cvt_bf16x8(lo, hi);
}

// Zero-LDS, zero-barrier GEMM. Block = 256 thr = 4 waves.
// Block tile: 32 n-rows x ALL 512 o (each wave owns a 128-o quarter) -> every x row
// is fetched by exactly one block. W (bf16, preconverted) is 512 KiB/channel and
// stays L2-resident on its XCD (c = bid&7 pins channel -> XCD under %8 round-robin).
// A frags: global fp32 -> regs -> cvt_pk -> MFMA A operand (no LDS round trip).
// B frags: global bf16 (L2 hit) -> regs. All k offsets are compile-time immediates.
template <bool PRE>
__device__ __forceinline__ void gemm_body(const float* __restrict__ xg,
                                          const void* __restrict__ wsrc,
                                          const float* __restrict__ bg,
                                          float* __restrict__ og) {
  const int bid  = blockIdx.x;
  const int c    = bid & 7;
  const int n0   = (bid >> 3) * 32;
  const int tid  = (int)threadIdx.x;
  const int lane = tid & 63;
  const int wv   = tid >> 6;   // 0..3 -> o quarter
  const int o0   = wv * 128;
  const int fl   = lane & 15;  // fragment row (n for A, o for B), D col
  const int quad = lane >> 4;  // k sub-offset *8 ; D row = quad*4 + r

  // A bases: lane reads 8 consecutive k floats of row (n0 + mi*16 + fl)
  const float* ax0 = xg + ((size_t)(n0 + fl) * C_CH + c) * K_IN + quad * 8;
  const float* ax1 = ax0 + (size_t)16 * C_CH * K_IN;

  // B bases per ni (o-group): row (o0 + ni*16 + fl), 8 k at quad*8
  const unsigned short* bx[8];
  const float* bxf[8];
#pragma unroll
  for (int ni = 0; ni < 8; ++ni) {
    const size_t off = ((size_t)c * OUT_F + o0 + ni * 16 + fl) * K_IN + quad * 8;
    bx[ni]  = (const unsigned short*)wsrc + off;
    bxf[ni] = (const float*)wsrc + off;
  }

  f32x4 acc[2][8];
#pragma unroll
  for (int mi = 0; mi < 2; ++mi)
#pragma unroll
    for (int ni = 0; ni < 8; ++ni)
#pragma unroll
      for (int e = 0; e < 4; ++e) acc[mi][ni][e] = 0.0f;

  // prologue: k-step 0 A loads
  f32x4 al0 = *(const f32x4*)(ax0);
  f32x4 ah0 = *(const f32x4*)(ax0 + 4);
  f32x4 al1 = *(const f32x4*)(ax1);
  f32x4 ah1 = *(const f32x4*)(ax1 + 4);

#pragma unroll
  for (int ks = 0; ks < NKS; ++ks) {
    // B for this k-step (L2-resident bf16; imm-offset loads)
    s16x8 bf[8];
    if constexpr (PRE) {
#pragma unroll
      for (int ni = 0; ni < 8; ++ni)
        bf[ni] = *(const s16x8*)(bx[ni] + ks * 32);
    } else {
#pragma unroll
      for (int ni = 0; ni < 8; ++ni) {
        f32x4 blo = *(const f32x4*)(bxf[ni] + ks * 32);
        f32x4 bhi = *(const f32x4*)(bxf[ni] + ks * 32 + 4);
        bf[ni] = cvt_bf16x8(blo, bhi);
      }
    }
    // prefetch next k-step A (HBM) - stays in flight through the MFMAs
    f32x4 nl0, nh0, nl1, nh1;
    if (ks + 1 < NKS) {
      nl0 = *(const f32x4*)(ax0 + (ks + 1) * 32);
      nh0 = *(const f32x4*)(ax0 + (ks + 1) * 32 + 4);
      nl1 = *(const f32x4*)(ax1 + (ks + 1) * 32);
      nh1 = *(const f32x4*)(ax1 + (ks + 1) * 32 + 4);
    }
    const s16x8 af0 = cvt_bf16x8(al0, ah0);
    const s16x8 af1 = cvt_bf16x8(al1, ah1);
#pragma unroll
    for (int ni = 0; ni < 8; ++ni) {
      acc[0][ni] = __builtin_amdgcn_mfma_f32_16x16x32_bf16(af0, bf[ni], acc[0][ni], 0, 0, 0);
      acc[1][ni] = __builtin_amdgcn_mfma_f32_16x16x32_bf16(af1, bf[ni], acc[1][ni], 0, 0, 0);
    }
    if (ks + 1 < NKS) { al0 = nl0; ah0 = nh0; al1 = nl1; ah1 = nh1; }
  }

  // epilogue: D layout col(o) = fl, row(n) = quad*4 + r (+ mi*16)
  float bias[8];
#pragma unroll
  for (int ni = 0; ni < 8; ++ni)
    bias[ni] = bg[c * OUT_F + o0 + ni * 16 + fl];

#pragma unroll
  for (int mi = 0; mi < 2; ++mi) {
#pragma unroll
    for (int r = 0; r < 4; ++r) {
      const size_t n = (size_t)n0 + mi * 16 + quad * 4 + r;
      float* orow = og + (n * C_CH + c) * OUT_F + o0 + fl;
#pragma unroll
      for (int ni = 0; ni < 8; ++ni)
        __builtin_nontemporal_store(acc[mi][ni][r] + bias[ni], orow + ni * 16);
    }
  }
}

extern "C" __global__ void __launch_bounds__(256, 2)
mcl_gemm_pre(const float* __restrict__ xg, const unsigned short* __restrict__ wb,
             const float* __restrict__ bg, float* __restrict__ og) {
  gemm_body<true>(xg, wb, bg, og);
}

extern "C" __global__ void __launch_bounds__(256, 2)
mcl_gemm_f32(const float* __restrict__ xg, const float* __restrict__ wg,
             const float* __restrict__ bg, float* __restrict__ og) {
  gemm_body<false>(xg, wg, bg, og);
}

extern "C" void kernel_launch(void* const* d_in, const int* in_sizes, int n_in,
                              void* d_out, int out_size, void* d_ws, size_t ws_size,
                              hipStream_t stream) {
  const float* x = (const float*)d_in[0];
  const float* W = (const float*)d_in[1];
  const float* b = (const float*)d_in[2];
  float* out = (float*)d_out;

  dim3 grid(C_CH * (N_TOT / 32)); // 8192 blocks; bid&7 = channel -> XCD pinning
  if (d_ws && ws_size >= WB_ELEMS * sizeof(unsigned short)) {
    unsigned short* wb = (unsigned short*)d_ws;
    wconv<<<dim3((unsigned)(WB_ELEMS / (256 * 8))), dim3(256), 0, stream>>>(W, wb);
    mcl_gemm_pre<<<grid, dim3(256), 0, stream>>>(x, wb, b, out);
  } else {
    // workspace too small: same structure, read fp32 W directly (still L2-resident/channel)
    mcl_gemm_f32<<<grid, dim3(256), 0, stream>>>(x, W, b, out);
  }
}